// Round 5
// baseline (66.946 us; speedup 1.0000x reference)
//
#include <hip/hip_runtime.h>

// B=2, S=2048, D_MODEL=1024, H=16, E=64.  Inputs/outputs FLOAT32.
// out = Q (norm * K^T V)  -- reassociated, no S x S scores.
// convert_pack -> qkv_gemm (256x192 tile, 2-buffer ring, counted vmcnt,
// transposed epilogue -> Qt/Kt/Vt[bh][64][2048]) -> kv_outer (MFMA) ->
// qm_out (fused 8-partial reduce + Q.M).

typedef __attribute__((ext_vector_type(8))) __bf16 bf16x8;
typedef __attribute__((ext_vector_type(8))) short short8;
typedef __attribute__((ext_vector_type(4))) float f32x4;
typedef __attribute__((ext_vector_type(4))) unsigned short ushort4v;

#define NX  4194304   // 4096*1024
#define NW1 1048576   // 1024*1024
#define NW  3145728   // 3*NW1

__device__ __forceinline__ float bf2f(unsigned short u) {
  union { unsigned int i; float f; } v; v.i = ((unsigned int)u) << 16; return v.f;
}
__device__ __forceinline__ unsigned short f2bf(float f) {
  union { float f; unsigned int i; } v; v.f = f;
  unsigned int u = v.i;
  u += 0x7fffu + ((u >> 16) & 1u);   // RNE
  return (unsigned short)(u >> 16);
}

__device__ __forceinline__ void gload_lds16(const void* g, void* l) {
  __builtin_amdgcn_global_load_lds(
      (const __attribute__((address_space(1))) void*)(unsigned long long)(g),
      (__attribute__((address_space(3))) void*)(unsigned int)(unsigned long long)(l),
      16, 0, 0);
}

// ---------------------------------------------------------------------------
// Kernel 0: f32 -> bf16 convert/pack.
// ---------------------------------------------------------------------------
__global__ __launch_bounds__(256) void convert_pack(
    const float* __restrict__ x,
    const float* __restrict__ wq, const float* __restrict__ wk,
    const float* __restrict__ wv,
    const float* __restrict__ bq, const float* __restrict__ bk,
    const float* __restrict__ bv,
    unsigned short* __restrict__ Xbf, unsigned short* __restrict__ Wcat,
    float* __restrict__ Bcat)
{
  const long long t8 = ((long long)blockIdx.x * 256 + threadIdx.x) * 8;
  const float* src;
  unsigned short* dst;
  long long off;
  if (t8 < NX) {
    src = x; dst = Xbf; off = t8;
  } else if (t8 < NX + NW) {
    const long long w = t8 - NX;
    const int z = (int)(w >> 20);
    off = w & (NW1 - 1);
    src = (z == 0) ? wq : (z == 1) ? wk : wv;
    dst = Wcat + (long long)z * NW1;
  } else if (t8 < NX + NW + 3072) {
    const long long bo = t8 - (NX + NW);
    const int z = (int)(bo >> 10);
    const long long o2 = bo & 1023;
    const float* bsrc = (z == 0) ? bq : (z == 1) ? bk : bv;
    *(f32x4*)(Bcat + z * 1024 + o2)     = *(const f32x4*)(bsrc + o2);
    *(f32x4*)(Bcat + z * 1024 + o2 + 4) = *(const f32x4*)(bsrc + o2 + 4);
    return;
  } else {
    return;
  }
  f32x4 v0 = *(const f32x4*)(src + off);
  f32x4 v1 = *(const f32x4*)(src + off + 4);
  union { short8 s; unsigned short u[8]; } o;
#pragma unroll
  for (int j = 0; j < 4; ++j) {
    o.u[j]     = f2bf(v0[j]);
    o.u[4 + j] = f2bf(v1[j]);
  }
  *(short8*)(dst + off) = o.s;
}

// ---------------------------------------------------------------------------
// Kernel 1: C[r,c] = sum_d Xbf[r,d]*Wcat[c,d] + Bcat[c].
// R=4096, C=3072, K=1024.  BM=256 x BN=192 tile, BK=64, 8 waves (2M x 4N),
// grid 16x16 = 256 blocks (100% CU coverage), 2-buffer LDS ring (112 KB),
// counted vmcnt(7) -- loads stay in flight across barriers.
// Per step: read 22 frags -> lgkmcnt(0)+barrier -> stage kt+2 (7 gload_lds)
// -> 48 MFMA -> vmcnt(7)+barrier.
// Epilogue: transposed per-head stores Qt/Kt/Vt[bh][64][2048], 8B packed.
// ---------------------------------------------------------------------------
#define ABYTES 32768          // 256*64*2
#define BBYTES 24576          // 192*64*2
#define BUFB   57344          // ABYTES+BBYTES
__global__ __launch_bounds__(512, 2) void qkv_gemm(
    const unsigned short* __restrict__ Xbf,
    const unsigned short* __restrict__ Wcat,
    const float* __restrict__ Bcat,
    unsigned short* __restrict__ Qt,
    unsigned short* __restrict__ Kt,
    unsigned short* __restrict__ Vt)
{
  __shared__ unsigned char lds[2 * BUFB];   // 112 KB

  const int tid = threadIdx.x;
  int bid = blockIdx.x;
  bid = (bid & 7) * 32 + (bid >> 3);        // bijective XCD swizzle (256%8==0)
  const int colBase = (bid & 15) * 192;     // 16 col tiles
  const int rowBase = (bid >> 4) * 256;     // 16 row tiles

  const int lane = tid & 63;
  const int wid  = tid >> 6;                // 0..7
  const int wm = wid >> 2;                  // 0..1
  const int wn = wid & 3;                   // 0..3
  const int wr = wm * 128;
  const int wc = wn * 48;
  const int lr = lane & 15;
  const int lk = lane >> 4;

  // staging addresses (constant per thread except kt, buf)
  const int sArow[4] = { (0*512+tid) >> 3, (1*512+tid) >> 3,
                         (2*512+tid) >> 3, (3*512+tid) >> 3 };
  const int sseg = tid & 7;                 // seg of si (si&7 == tid&7)

  f32x4 acc[8][3] = {};

#define STAGE(buf, kt)                                                        \
  {                                                                           \
    const int k0_ = (kt) * 64;                                                \
    _Pragma("unroll")                                                         \
    for (int i_ = 0; i_ < 4; ++i_) {                                          \
      const int row_ = sArow[i_];                                             \
      const int ss_ = sseg ^ (row_ & 7);                                      \
      gload_lds16(Xbf + (size_t)(rowBase + row_) * 1024 + k0_ + ss_ * 8,      \
                  lds + (buf) * BUFB + (i_ * 512 + tid) * 16);                \
    }                                                                         \
    _Pragma("unroll")                                                         \
    for (int i_ = 0; i_ < 3; ++i_) {                                          \
      const int row_ = sArow[i_];                                             \
      const int ss_ = sseg ^ (row_ & 7);                                      \
      gload_lds16(Wcat + (size_t)(colBase + row_) * 1024 + k0_ + ss_ * 8,     \
                  lds + (buf) * BUFB + ABYTES + (i_ * 512 + tid) * 16);       \
    }                                                                         \
  }

  // prologue: stage kt0 -> buf0, kt1 -> buf1; wait kt0 landed (kt1 in flight)
  STAGE(0, 0);
  STAGE(1, 1);
  asm volatile("s_waitcnt vmcnt(7)" ::: "memory");
  __builtin_amdgcn_s_barrier();

  for (int t = 0; t < 16; ++t) {
    const int cur = t & 1;
    const unsigned char* Ab = lds + cur * BUFB;
    const unsigned char* Bb = Ab + ABYTES;

    bf16x8 af[2][8], bvf[2][3];
#pragma unroll
    for (int ks = 0; ks < 2; ++ks) {
#pragma unroll
      for (int m = 0; m < 8; ++m) {
        const int row = wr + m * 16 + lr;
        af[ks][m] = *(const bf16x8*)(Ab + row * 128 +
                                     (((ks * 4 + lk) ^ (row & 7)) * 16));
      }
#pragma unroll
      for (int n = 0; n < 3; ++n) {
        const int row = wc + n * 16 + lr;
        bvf[ks][n] = *(const bf16x8*)(Bb + row * 128 +
                                      (((ks * 4 + lk) ^ (row & 7)) * 16));
      }
    }
    // all this wave's reads complete; barrier => all waves done reading cur
    asm volatile("s_waitcnt lgkmcnt(0)" ::: "memory");
    __builtin_amdgcn_s_barrier();

    if (t + 2 < 16) STAGE(cur, t + 2);      // overwrite just-consumed buffer

#pragma unroll
    for (int ks = 0; ks < 2; ++ks)
#pragma unroll
      for (int m = 0; m < 8; ++m)
#pragma unroll
        for (int n = 0; n < 3; ++n)
          acc[m][n] = __builtin_amdgcn_mfma_f32_16x16x32_bf16(
              af[ks][m], bvf[ks][n], acc[m][n], 0, 0, 0);

    // drain kt t+1 only; keep kt t+2's 7 loads in flight
    if (t < 13) asm volatile("s_waitcnt vmcnt(7)" ::: "memory");
    else        asm volatile("s_waitcnt vmcnt(0)" ::: "memory");
    __builtin_amdgcn_s_barrier();
  }
#undef STAGE

  // Epilogue.  D mapping: col = lane&15 (lr), row = lk*4 + j.
  const int bB = rowBase >> 11;             // batch
#pragma unroll
  for (int n = 0; n < 3; ++n) {
    const int colG = colBase + wc + n * 16 + lr;
    const float bval = Bcat[colG];
    const int zone = colG >> 10;            // uniform per frag (16-aligned)
    unsigned short* __restrict__ T = (zone == 0) ? Qt : (zone == 1) ? Kt : Vt;
    const int hf = (colG >> 6) & 15;
    const int f  = colG & 63;
    const size_t rowOff = ((size_t)(bB * 16 + hf) * 64 + f) * 2048;
#pragma unroll
    for (int m = 0; m < 8; ++m) {
      const int t = (rowBase + wr + m * 16 + lk * 4) & 2047;
      ushort4v pk;
#pragma unroll
      for (int j = 0; j < 4; ++j)
        pk[j] = f2bf(acc[m][n][j] + bval);
      *(ushort4v*)&T[rowOff + t] = pk;
    }
  }
}

// ---------------------------------------------------------------------------
// Kernel 2 (MFMA): Mpart[blk][f][e] = sum_{t in chunk} Kt[bh][f][t]*Vt[bh][e][t]
// grid 256 blocks x 64 threads (1 wave).  blk = bh*8 + tchunk.
// ---------------------------------------------------------------------------
__global__ __launch_bounds__(64) void kv_outer(
    const unsigned short* __restrict__ Kt,
    const unsigned short* __restrict__ Vt,
    float* __restrict__ Mpart)
{
  const int lane = threadIdx.x;
  const int blk = blockIdx.x;
  const int bh = blk >> 3, tc = blk & 7;
  const int lr = lane & 15, lk = lane >> 4;
  const size_t base = (size_t)bh * 64 * 2048;

  f32x4 acc[4][4] = {};
#pragma unroll
  for (int ks = 0; ks < 8; ++ks) {
    const int t0 = tc * 256 + ks * 32 + lk * 8;
    bf16x8 af[4], bf[4];
#pragma unroll
    for (int m = 0; m < 4; ++m)
      af[m] = *(const bf16x8*)&Kt[base + (size_t)(m * 16 + lr) * 2048 + t0];
#pragma unroll
    for (int n = 0; n < 4; ++n)
      bf[n] = *(const bf16x8*)&Vt[base + (size_t)(n * 16 + lr) * 2048 + t0];
#pragma unroll
    for (int m = 0; m < 4; ++m)
#pragma unroll
      for (int n = 0; n < 4; ++n)
        acc[m][n] = __builtin_amdgcn_mfma_f32_16x16x32_bf16(af[m], bf[n], acc[m][n], 0, 0, 0);
  }
  float* out = Mpart + (size_t)blk * 4096;
#pragma unroll
  for (int m = 0; m < 4; ++m)
#pragma unroll
    for (int n = 0; n < 4; ++n)
#pragma unroll
      for (int j = 0; j < 4; ++j)
        out[(m * 16 + lk * 4 + j) * 64 + n * 16 + lr] = acc[m][n][j];
}

// ---------------------------------------------------------------------------
// Kernel 3: Out[s, h*64+e] = sum_f Qt[bh][f][s] * (norm * sum_ch Mpart)[f][e]
// Fused 8-partial reduce + Q.M.  grid (16 s-chunks, 16 h, 2 b), 256 thr.
// ---------------------------------------------------------------------------
__global__ __launch_bounds__(256) void qm_out(
    const unsigned short* __restrict__ Qt, const float* __restrict__ Mpart,
    float* __restrict__ Out)
{
  __shared__ float Ms[64 * 64];      // 16 KB
  __shared__ float Qst[64 * 132];    // [f][s] padded, ~33 KB
  const int tid = threadIdx.x;
  const int b = blockIdx.z, h = blockIdx.y, s0 = blockIdx.x * 128;
  const int bh = b * 16 + h;

#pragma unroll
  for (int i = 0; i < 4; ++i) {
    const int off = i * 1024 + tid * 4;
    f32x4 s = {};
#pragma unroll
    for (int ch = 0; ch < 8; ++ch)
      s += *(const f32x4*)&Mpart[((size_t)bh * 8 + ch) * 4096 + off];
    s *= 0.125f;   // 64^-0.5
    *(f32x4*)&Ms[off] = s;
  }
  const size_t qbase = (size_t)bh * 64 * 2048;
#pragma unroll
  for (int i = 0; i < 4; ++i) {
    const int slot = i * 256 + tid;          // 0..1023
    const int f = slot >> 4, c = slot & 15;
    short8 q = *(const short8*)&Qt[qbase + (size_t)f * 2048 + s0 + c * 8];
#pragma unroll
    for (int j = 0; j < 8; ++j)
      Qst[f * 132 + c * 8 + j] = bf2f((unsigned short)q[j]);
  }
  __syncthreads();

  const int s = (tid >> 3) * 4;       // 4 rows / thread
  const int e0 = (tid & 7) * 8;       // 8 cols / thread
  float acc2[4][8] = {};
  for (int f = 0; f < 64; ++f) {
    f32x4 m0 = *(const f32x4*)&Ms[f * 64 + e0];
    f32x4 m1 = *(const f32x4*)&Ms[f * 64 + e0 + 4];
#pragma unroll
    for (int i = 0; i < 4; ++i) {
      const float q = Qst[f * 132 + s + i];
#pragma unroll
      for (int j = 0; j < 4; ++j) {
        acc2[i][j]     += q * m0[j];
        acc2[i][j + 4] += q * m1[j];
      }
    }
  }
  const size_t obase = ((size_t)b * 2048 + s0) * 1024 + h * 64;
#pragma unroll
  for (int i = 0; i < 4; ++i) {
    f32x4 o0 = { acc2[i][0], acc2[i][1], acc2[i][2], acc2[i][3] };
    f32x4 o1 = { acc2[i][4], acc2[i][5], acc2[i][6], acc2[i][7] };
    *(f32x4*)&Out[obase + (size_t)(s + i) * 1024 + e0]     = o0;
    *(f32x4*)&Out[obase + (size_t)(s + i) * 1024 + e0 + 4] = o1;
  }
}

extern "C" void kernel_launch(void* const* d_in, const int* in_sizes, int n_in,
                              void* d_out, int out_size, void* d_ws, size_t ws_size,
                              hipStream_t stream) {
  const float* x  = (const float*)d_in[0];
  const float* Wq = (const float*)d_in[1];
  const float* Wk = (const float*)d_in[2];
  const float* Wv = (const float*)d_in[3];
  const float* bq = (const float*)d_in[4];
  const float* bk = (const float*)d_in[5];
  const float* bv = (const float*)d_in[6];
  float* out = (float*)d_out;

  char* ws = (char*)d_ws;
  const size_t MiB = 1024ull * 1024ull;
  unsigned short* Xbf   = (unsigned short*)(ws);              //  8 MiB
  unsigned short* Wcat  = (unsigned short*)(ws + 8  * MiB);   //  6 MiB
  float*          Bcat  = (float*)         (ws + 14 * MiB);   // 12 KiB
  unsigned short* Qt    = (unsigned short*)(ws + 15 * MiB);   //  8 MiB
  unsigned short* Kt    = (unsigned short*)(ws + 23 * MiB);   //  8 MiB
  unsigned short* Vt    = (unsigned short*)(ws + 31 * MiB);   //  8 MiB
  float*          Mpart = (float*)         (ws + 39 * MiB);   //  4 MiB

  convert_pack<<<3586, 256, 0, stream>>>(x, Wq, Wk, Wv, bq, bk, bv,
                                         Xbf, Wcat, Bcat);
  qkv_gemm<<<256, 512, 0, stream>>>(Xbf, Wcat, Bcat, Qt, Kt, Vt);
  kv_outer<<<256, 64, 0, stream>>>(Kt, Vt, Mpart);
  qm_out<<<dim3(16, 16, 2), 256, 0, stream>>>(Qt, Mpart, out);
}